// Round 1
// baseline (26115.375 us; speedup 1.0000x reference)
//
#include <hip/hip_runtime.h>
#include <math.h>

#define H    256
#define BB   64
#define LL   128
#define LBL  128
#define NSTEP (BB*LL)      // 8192 sequential cell steps
#define GDIM (4*H)         // 1024 gate rows
#define KDIM (4*H)         // 1024 feats dim
#define W5   (5*H)         // 1280 (W_ih leading dim)
#define NWG  16            // recurrence team size

// ---------------------------------------------------------------------------
// K1: PRE[k][row] = bias[row] + sum_j W_ih[row][j] * feats[k][j], j<1024
//     k = t*64 + b ; feats[k][j] = (j<512 ? x[b][t][j] : hi[b][t][j-512])
//     Tiled fp32 GEMM, 64x64 tile, BK=16, 256 threads, 4x4 microtile.
// ---------------------------------------------------------------------------
__global__ __launch_bounds__(256) void k_pre(const float* __restrict__ x,
                                             const float* __restrict__ hi,
                                             const float* __restrict__ Wih,
                                             const float* __restrict__ bih,
                                             const float* __restrict__ bhh,
                                             float* __restrict__ PRE)
{
    const int nb = blockIdx.x;   // row-block: rows nb*64 .. +63
    const int t  = blockIdx.y;   // time index == M-block (m_local = b)
    const int tid = threadIdx.x;
    const int tm = tid >> 4, tn = tid & 15;

    __shared__ float As[16][68];   // [kk][m_local], padded, 16B-aligned rows
    __shared__ float Bs[16][68];   // [kk][n_local]

    const int lm  = tid >> 2;          // 0..63
    const int lk4 = (tid & 3) * 4;     // 0,4,8,12

    float acc[4][4];
#pragma unroll
    for (int i = 0; i < 4; i++)
#pragma unroll
        for (int j = 0; j < 4; j++) acc[i][j] = 0.f;

    for (int j0 = 0; j0 < KDIM; j0 += 16) {
        const int j = j0 + lk4;
        float4 av;
        if (j < 512) av = *(const float4*)(x  + ((size_t)lm * LL + t) * 512 + j);
        else         av = *(const float4*)(hi + ((size_t)lm * LL + t) * 512 + (j - 512));
        float4 bv = *(const float4*)(Wih + (size_t)(nb * 64 + lm) * W5 + j);

        __syncthreads();   // protect LDS from previous iteration's readers
        As[lk4 + 0][lm] = av.x; As[lk4 + 1][lm] = av.y;
        As[lk4 + 2][lm] = av.z; As[lk4 + 3][lm] = av.w;
        Bs[lk4 + 0][lm] = bv.x; Bs[lk4 + 1][lm] = bv.y;
        Bs[lk4 + 2][lm] = bv.z; Bs[lk4 + 3][lm] = bv.w;
        __syncthreads();

#pragma unroll
        for (int kk = 0; kk < 16; kk++) {
            float4 a = *(const float4*)&As[kk][tm << 2];
            float4 b = *(const float4*)&Bs[kk][tn << 2];
            acc[0][0] += a.x * b.x; acc[0][1] += a.x * b.y; acc[0][2] += a.x * b.z; acc[0][3] += a.x * b.w;
            acc[1][0] += a.y * b.x; acc[1][1] += a.y * b.y; acc[1][2] += a.y * b.z; acc[1][3] += a.y * b.w;
            acc[2][0] += a.z * b.x; acc[2][1] += a.z * b.y; acc[2][2] += a.z * b.z; acc[2][3] += a.z * b.w;
            acc[3][0] += a.w * b.x; acc[3][1] += a.w * b.y; acc[3][2] += a.w * b.z; acc[3][3] += a.w * b.w;
        }
    }

    const int n0 = nb * 64 + tn * 4;
    float4 b1 = *(const float4*)(bih + n0);
    float4 b2 = *(const float4*)(bhh + n0);
    const float bx = b1.x + b2.x, by = b1.y + b2.y, bz = b1.z + b2.z, bw = b1.w + b2.w;
#pragma unroll
    for (int i = 0; i < 4; i++) {
        const size_t m = (size_t)t * 64 + tm * 4 + i;    // k index
        float4 o;
        o.x = acc[i][0] + bx; o.y = acc[i][1] + by;
        o.z = acc[i][2] + bz; o.w = acc[i][3] + bw;
        *(float4*)&PRE[m * GDIM + n0] = o;
    }
}

// ---------------------------------------------------------------------------
// K2: sequential recurrence, cooperative 16-WG team, fp32 weights in VGPRs.
//   g_k[row] = PRE[k][row] + W_hh[row]·h_{k-1} + W_o[row]·h_{k-64}
//   WG g owns h elements j in [g*16, g*16+16) and the 4 gate rows per j.
//   HBUF[(k+64)*H + j] = h_k[j]; rows 0..63 pre-zeroed (initial h / out_prev).
//   done[g] = number of steps WG g has completed (release/acquire, agent).
// ---------------------------------------------------------------------------
__global__ __launch_bounds__(1024) void k_rec(const float* __restrict__ PRE,
                                              const float* __restrict__ Wih,
                                              const float* __restrict__ Whh,
                                              float* HBUF, int* done)
{
    const int g   = blockIdx.x;
    const int tid = threadIdx.x;
    const int rt  = tid >> 4;      // 0..63 row task
    const int kc  = tid & 15;      // K-lane within row
    const int gate = rt >> 4;      // 0..3 (i,f,g~,o)
    const int jj   = rt & 15;      // element within WG's h slice
    const int row  = gate * 256 + g * 16 + jj;

    float whh[16], wo[16];
#pragma unroll
    for (int i = 0; i < 16; i++) whh[i] = Whh[(size_t)row * H + kc * 16 + i];
#pragma unroll
    for (int i = 0; i < 16; i++) wo[i]  = Wih[(size_t)row * W5 + 4 * H + kc * 16 + i];

    __shared__ float h1s[256];    // h_{k-1}
    __shared__ float h64s[256];   // h_{k-64} (out_prev)
    __shared__ float gbuf[64];    // gate pre-activations for owned rows

    float c_reg = 0.f;                     // valid for tid<16: c[g*16+tid]
    long long spin_budget = 30000000LL;    // shared across steps: bounded exit

    for (int k = 0; k < NSTEP; k++) {
        // PRE prefetch (no h dependency) — overlaps the spin below
        float pre = 0.f;
        if (kc == 0) pre = PRE[(size_t)k * GDIM + row];

        if (k > 0 && tid < NWG) {
            while (__hip_atomic_load(&done[tid], __ATOMIC_ACQUIRE,
                                     __HIP_MEMORY_SCOPE_AGENT) < k) {
                if (--spin_budget < 0) break;
            }
        }
        __syncthreads();

        // stage h_{k-1} and h_{k-64} into LDS (L2-bypassing agent loads)
        if (tid < 512) {
            const int e = tid & 255;
            const size_t srow = (tid < 256) ? ((size_t)(k + 63) * H + e)
                                            : ((size_t)k * H + e);
            float v = __hip_atomic_load(&HBUF[srow], __ATOMIC_RELAXED,
                                        __HIP_MEMORY_SCOPE_AGENT);
            if (tid < 256) h1s[e] = v; else h64s[e] = v;
        }
        __syncthreads();

        // 32-MAC partial dot per thread
        float acc = 0.f;
        const float4* h1v  = (const float4*)&h1s[kc * 16];
        const float4* h64v = (const float4*)&h64s[kc * 16];
#pragma unroll
        for (int q = 0; q < 4; q++) {
            float4 a = h1v[q];
            acc += whh[4*q+0]*a.x + whh[4*q+1]*a.y + whh[4*q+2]*a.z + whh[4*q+3]*a.w;
            float4 b = h64v[q];
            acc += wo[4*q+0]*b.x + wo[4*q+1]*b.y + wo[4*q+2]*b.z + wo[4*q+3]*b.w;
        }
        // reduce across the 16 K-lanes (lanes differ only in kc bits 0..3)
        acc += __shfl_xor(acc, 8);
        acc += __shfl_xor(acc, 4);
        acc += __shfl_xor(acc, 2);
        acc += __shfl_xor(acc, 1);
        if (kc == 0) gbuf[rt] = acc + pre;
        __syncthreads();

        // gate combine + state update + publish (all within wave 0)
        if (tid < 16) {
            float iv = 1.f / (1.f + __expf(-gbuf[tid]));
            float fv = 1.f / (1.f + __expf(-gbuf[16 + tid]));
            float gv = tanhf(gbuf[32 + tid]);
            float ov = 1.f / (1.f + __expf(-gbuf[48 + tid]));
            c_reg = fv * c_reg + iv * gv;
            float h = ov * tanhf(c_reg);
            HBUF[(size_t)(k + 64) * H + g * 16 + tid] = h;
        }
        // release-store orders wave 0's prior h stores (waitcnt + wbl2)
        if (tid == 0)
            __hip_atomic_store(&done[g], k + 1, __ATOMIC_RELEASE,
                               __HIP_MEMORY_SCOPE_AGENT);
        __syncthreads();
    }
}

// ---------------------------------------------------------------------------
// K3: out[b][t][l] = b_fc[l] + sum_j h_k[j] * W_fc[l][j],  k = t*64+b
//     8 k-rows per block; W_fc chunk-staged in LDS with +65 stride.
// ---------------------------------------------------------------------------
__global__ __launch_bounds__(256) void k_fc(const float* __restrict__ HBUF,
                                            const float* __restrict__ Wfc,
                                            const float* __restrict__ bfc,
                                            float* __restrict__ out)
{
    __shared__ float hl[8 * 256];
    __shared__ float wl[128 * 65];
    const int blk = blockIdx.x;     // 0..1023, k = blk*8 + kk
    const int tid = threadIdx.x;

#pragma unroll
    for (int kk = 0; kk < 8; kk++)
        hl[kk * 256 + tid] = HBUF[((size_t)(blk * 8 + kk + 64)) * H + tid];

    const int l = tid & 127, grp = tid >> 7;
    float a0 = 0.f, a1 = 0.f, a2 = 0.f, a3 = 0.f;

    for (int c = 0; c < 4; c++) {
        __syncthreads();   // orders hl (c==0) and wl reuse (c>0)
        for (int m = 0; m < 32; m++) {
            const int idx = m * 256 + tid;
            const int lr = idx >> 6, jc = idx & 63;
            wl[lr * 65 + jc] = Wfc[(size_t)lr * H + c * 64 + jc];
        }
        __syncthreads();
#pragma unroll 4
        for (int jc = 0; jc < 64; jc++) {
            const float w = wl[l * 65 + jc];
            const int hj = c * 64 + jc;
            a0 += hl[(grp * 4 + 0) * 256 + hj] * w;
            a1 += hl[(grp * 4 + 1) * 256 + hj] * w;
            a2 += hl[(grp * 4 + 2) * 256 + hj] * w;
            a3 += hl[(grp * 4 + 3) * 256 + hj] * w;
        }
    }

    const float bias = bfc[l];
    float accs[4] = {a0, a1, a2, a3};
#pragma unroll
    for (int r = 0; r < 4; r++) {
        const int k = blk * 8 + grp * 4 + r;
        const int t = k >> 6, b = k & 63;
        out[((size_t)b * LL + t) * LBL + l] = accs[r] + bias;
    }
}

// ---------------------------------------------------------------------------
extern "C" void kernel_launch(void* const* d_in, const int* in_sizes, int n_in,
                              void* d_out, int out_size, void* d_ws, size_t ws_size,
                              hipStream_t stream)
{
    const float* x   = (const float*)d_in[0];
    const float* hi  = (const float*)d_in[1];
    const float* Wih = (const float*)d_in[2];
    const float* Whh = (const float*)d_in[3];
    const float* bih = (const float*)d_in[4];
    const float* bhh = (const float*)d_in[5];
    const float* Wfc = (const float*)d_in[6];
    const float* bfc = (const float*)d_in[7];
    float* out = (float*)d_out;

    float* PRE  = (float*)d_ws;                                  // 8192*1024 f32
    float* HBUF = PRE + (size_t)NSTEP * GDIM;                    // (8192+64)*256 f32
    int*   done = (int*)(HBUF + (size_t)(NSTEP + 64) * H);       // 16 ints

    const size_t need = ((size_t)NSTEP * GDIM + (size_t)(NSTEP + 64) * H) * sizeof(float)
                        + NWG * sizeof(int);
    if (ws_size < need) return;   // visible failure instead of OOB writes

    // zero initial h rows (h_{-1} and out_prev for t=0) and the flags
    hipMemsetAsync(HBUF, 0, (size_t)64 * H * sizeof(float), stream);
    hipMemsetAsync(done, 0, NWG * sizeof(int), stream);

    k_pre<<<dim3(GDIM / 64, LL), 256, 0, stream>>>(x, hi, Wih, bih, bhh, PRE);
    k_rec<<<NWG, 1024, 0, stream>>>(PRE, Wih, Whh, HBUF, done);
    k_fc<<<NSTEP / 8, 256, 0, stream>>>(HBUF, Wfc, bfc, out);
}

// Round 2
// 18509.373 us; speedup vs baseline: 1.4109x; 1.4109x over previous
//
#include <hip/hip_runtime.h>
#include <math.h>

#define H    256
#define BB   64
#define LL   128
#define LBL  128
#define NSTEP (BB*LL)      // 8192 sequential cell steps
#define GDIM (4*H)         // 1024 gate rows
#define KDIM (4*H)         // 1024 feats dim
#define W5   (5*H)         // 1280 (W_ih leading dim)
#define NWG  16            // recurrence team size
#define NROW (NSTEP + 64)  // tagged-h rows: row r holds h_{r-64}, tag r

typedef unsigned long long ull;

// LDS swizzle: insert one pad float per 16 -> 17*kc base, <=2-way banks (free)
#define SW(j) ((j) + ((j) >> 4))

// ---------------------------------------------------------------------------
// K0: init tagged rows 0..63 of HT: (h=0.0f, tag=row). Re-run every launch
//     (workspace is re-poisoned before every timed call).
// ---------------------------------------------------------------------------
__global__ void k_init(ull* __restrict__ HT)
{
    const int r = blockIdx.x;          // 0..63
    const int e = threadIdx.x;         // 0..255
    HT[(ull)r * H + e] = ((ull)(unsigned)r << 32);   // low 32 = 0.0f bits
}

// ---------------------------------------------------------------------------
// K1: PRE[k][row] = bias[row] + sum_j W_ih[row][j] * feats[k][j], j<1024
//     k = t*64 + b ; feats[k][j] = (j<512 ? x[b][t][j] : hi[b][t][j-512])
//     Tiled fp32 GEMM, 64x64 tile, BK=16, 256 threads, 4x4 microtile.
//     Output stored as fp16 (halves workspace + k_rec fetch; |pre|~O(5),
//     fp16 rel err ~1e-3 -> well under the 1.35e-2 output threshold).
// ---------------------------------------------------------------------------
__global__ __launch_bounds__(256) void k_pre(const float* __restrict__ x,
                                             const float* __restrict__ hi,
                                             const float* __restrict__ Wih,
                                             const float* __restrict__ bih,
                                             const float* __restrict__ bhh,
                                             _Float16* __restrict__ PREh)
{
    const int nb = blockIdx.x;   // row-block: rows nb*64 .. +63
    const int t  = blockIdx.y;   // time index == M-block (m_local = b)
    const int tid = threadIdx.x;
    const int tm = tid >> 4, tn = tid & 15;

    __shared__ float As[16][68];   // [kk][m_local], padded
    __shared__ float Bs[16][68];   // [kk][n_local]

    const int lm  = tid >> 2;          // 0..63
    const int lk4 = (tid & 3) * 4;     // 0,4,8,12

    float acc[4][4];
#pragma unroll
    for (int i = 0; i < 4; i++)
#pragma unroll
        for (int j = 0; j < 4; j++) acc[i][j] = 0.f;

    for (int j0 = 0; j0 < KDIM; j0 += 16) {
        const int j = j0 + lk4;
        float4 av;
        if (j < 512) av = *(const float4*)(x  + ((size_t)lm * LL + t) * 512 + j);
        else         av = *(const float4*)(hi + ((size_t)lm * LL + t) * 512 + (j - 512));
        float4 bv = *(const float4*)(Wih + (size_t)(nb * 64 + lm) * W5 + j);

        __syncthreads();   // protect LDS from previous iteration's readers
        As[lk4 + 0][lm] = av.x; As[lk4 + 1][lm] = av.y;
        As[lk4 + 2][lm] = av.z; As[lk4 + 3][lm] = av.w;
        Bs[lk4 + 0][lm] = bv.x; Bs[lk4 + 1][lm] = bv.y;
        Bs[lk4 + 2][lm] = bv.z; Bs[lk4 + 3][lm] = bv.w;
        __syncthreads();

#pragma unroll
        for (int kk = 0; kk < 16; kk++) {
            float4 a = *(const float4*)&As[kk][tm << 2];
            float4 b = *(const float4*)&Bs[kk][tn << 2];
            acc[0][0] += a.x * b.x; acc[0][1] += a.x * b.y; acc[0][2] += a.x * b.z; acc[0][3] += a.x * b.w;
            acc[1][0] += a.y * b.x; acc[1][1] += a.y * b.y; acc[1][2] += a.y * b.z; acc[1][3] += a.y * b.w;
            acc[2][0] += a.z * b.x; acc[2][1] += a.z * b.y; acc[2][2] += a.z * b.z; acc[2][3] += a.z * b.w;
            acc[3][0] += a.w * b.x; acc[3][1] += a.w * b.y; acc[3][2] += a.w * b.z; acc[3][3] += a.w * b.w;
        }
    }

    const int n0 = nb * 64 + tn * 4;
    float4 b1 = *(const float4*)(bih + n0);
    float4 b2 = *(const float4*)(bhh + n0);
    const float bx = b1.x + b2.x, by = b1.y + b2.y, bz = b1.z + b2.z, bw = b1.w + b2.w;
#pragma unroll
    for (int i = 0; i < 4; i++) {
        const size_t m = (size_t)t * 64 + tm * 4 + i;    // k index
        union { _Float16 h[4]; ull u; } p;
        p.h[0] = (_Float16)(acc[i][0] + bx);
        p.h[1] = (_Float16)(acc[i][1] + by);
        p.h[2] = (_Float16)(acc[i][2] + bz);
        p.h[3] = (_Float16)(acc[i][3] + bw);
        *(ull*)(PREh + m * GDIM + n0) = p.u;
    }
}

// ---------------------------------------------------------------------------
// K2: sequential recurrence, 16-WG team, LL-protocol tagged handoff.
//   HT row r (256 ull): (h_{r-64} bits, tag=r) packed 8B -> publish == sync.
//   WG g owns h elements [g*16, g*16+16); wave w owns element j=g*16+w.
//   Lane layout (64 lanes/wave): lane = gate*16 + kc.
//     acc = sum over K-slice kc: Whh[row][kc*16+i]*h1[..] + Wo[row][..]*h64[..]
//   Butterfly over kc -> per-gate sums; per-gate activation; 4 shuffles to
//   gather i,f,g,o in every lane; c redundant per lane; lane0 publishes.
//   One __syncthreads per step (double-buffered LDS h1s/h64s).
//   h64 (row k+1, published >=63 steps ago) and PRE are prefetched -> only
//   h1 (row k+64, just published) is on the critical path.
// ---------------------------------------------------------------------------
__device__ __forceinline__ float poll_pair(const ull* p, int want, long long& budget)
{
    ull v = __hip_atomic_load(p, __ATOMIC_RELAXED, __HIP_MEMORY_SCOPE_AGENT);
    while ((int)(v >> 32) != want) {
        if (--budget < 0) break;            // bounded exit on protocol failure
        v = __hip_atomic_load(p, __ATOMIC_RELAXED, __HIP_MEMORY_SCOPE_AGENT);
    }
    union { unsigned u; float f; } c; c.u = (unsigned)v;
    return c.f;
}

__global__ __launch_bounds__(1024) void k_rec(const _Float16* __restrict__ PREh,
                                              const float* __restrict__ Wih,
                                              const float* __restrict__ Whh,
                                              ull* __restrict__ HT)
{
    const int g    = blockIdx.x;        // 0..15
    const int tid  = threadIdx.x;
    const int w    = tid >> 6;          // wave id 0..15
    const int lane = tid & 63;
    const int gate = lane >> 4;         // 0..3 (i,f,g~,o)
    const int kc   = lane & 15;         // K-slice within row
    const int j_own = g * 16 + w;       // h element this wave owns
    const int row   = gate * H + j_own; // gate row in [0,1024)

    // register-resident weight slices: 16 + 16 floats
    float whh[16], wo[16];
#pragma unroll
    for (int i = 0; i < 16; i++) whh[i] = Whh[(size_t)row * H + kc * 16 + i];
#pragma unroll
    for (int i = 0; i < 16; i++) wo[i]  = Wih[(size_t)row * W5 + 4 * H + kc * 16 + i];

    __shared__ float h1s[2][272];    // h_{k-1}, swizzled
    __shared__ float h64s[2][272];   // h_{k-64}, swizzled

    long long budget = 8000000LL;

    // ---- prologue: stage buf0 with h1 row 63 (zeros) and h64 row 0 (zeros)
    if (lane < 32) {
        const int e  = (w << 4) + (kc);                 // kc == lane&15
        const int rw = (lane < 16) ? 63 : 0;
        float v = poll_pair(&HT[(ull)rw * H + e], rw, budget);
        if (lane < 16) h1s[0][SW(e)] = v; else h64s[0][SW(e)] = v;
    }
    float pre_cur = (float)PREh[row];   // k=0 (broadcast per 16 lanes)
    float c_state = 0.f;
    __syncthreads();

    for (int k = 0; k < NSTEP; ++k) {
        const int cb = k & 1, nb = cb ^ 1;

        // ---- compute: 32 MACs from swizzled LDS (<=2-way banks)
        float acc = 0.f;
        const int base = kc * 17;       // SW(kc*16)
#pragma unroll
        for (int q = 0; q < 4; ++q) {
            float4 a = *(const float4*)&h1s[cb][base + 4 * q];
            acc += whh[4*q+0]*a.x + whh[4*q+1]*a.y + whh[4*q+2]*a.z + whh[4*q+3]*a.w;
        }
#pragma unroll
        for (int q = 0; q < 4; ++q) {
            float4 b = *(const float4*)&h64s[cb][base + 4 * q];
            acc += wo[4*q+0]*b.x + wo[4*q+1]*b.y + wo[4*q+2]*b.z + wo[4*q+3]*b.w;
        }
        // butterfly over the 16 kc-lanes (stays inside each gate group)
        acc += __shfl_xor(acc, 1);
        acc += __shfl_xor(acc, 2);
        acc += __shfl_xor(acc, 4);
        acc += __shfl_xor(acc, 8);
        acc += pre_cur;

        // per-gate activation, then gather all 4 gates into every lane
        float act = (gate == 2) ? tanhf(acc) : 1.f / (1.f + __expf(-acc));
        const float iv = __shfl(act,      kc);
        const float fv = __shfl(act, 16 + kc);
        const float gv = __shfl(act, 32 + kc);
        const float ov = __shfl(act, 48 + kc);
        c_state = fv * c_state + iv * gv;
        const float h = ov * tanhf(c_state);

        // ---- publish (LL: data+tag in one 8B relaxed store; no fences)
        if (lane == 0) {
            union { float f; unsigned u; } cv; cv.f = h;
            __hip_atomic_store(&HT[(ull)(k + 64) * H + j_own],
                               ((ull)(unsigned)(k + 64) << 32) | cv.u,
                               __ATOMIC_RELAXED, __HIP_MEMORY_SCOPE_AGENT);
            h1s[nb][SW(j_own)] = h;     // own-WG shortcut: skip the IC trip
        }

        // ---- prefetch next PRE (off critical path)
        float pre_next = 0.f;
        if (k + 1 < NSTEP) pre_next = (float)PREh[(size_t)(k + 1) * GDIM + row];

        // ---- stage next-step buffers (h1 row k+64 hot; h64 row k+1 old)
        if (lane < 32) {
            const int e = (w << 4) + kc;
            const bool own = (lane < 16) && (w == g);   // staged via LDS above
            if (!own) {
                const int rw = (lane < 16) ? (k + 64) : (k + 1);
                float v = poll_pair(&HT[(ull)rw * H + e], rw, budget);
                if (lane < 16) h1s[nb][SW(e)] = v; else h64s[nb][SW(e)] = v;
            }
        }
        pre_cur = pre_next;
        __syncthreads();
    }
}

// ---------------------------------------------------------------------------
// K3: out[b][t][l] = b_fc[l] + sum_j h_k[j] * W_fc[l][j],  k = t*64+b
//     h read from tagged HT rows (low 32 bits). 8 k-rows per block.
// ---------------------------------------------------------------------------
__global__ __launch_bounds__(256) void k_fc(const ull* __restrict__ HT,
                                            const float* __restrict__ Wfc,
                                            const float* __restrict__ bfc,
                                            float* __restrict__ out)
{
    __shared__ float hl[8 * 256];
    __shared__ float wl[128 * 65];
    const int blk = blockIdx.x;     // 0..1023, k = blk*8 + kk
    const int tid = threadIdx.x;

#pragma unroll
    for (int kk = 0; kk < 8; kk++) {
        ull v = HT[((ull)(blk * 8 + kk + 64)) * H + tid];
        union { unsigned u; float f; } c; c.u = (unsigned)v;
        hl[kk * 256 + tid] = c.f;
    }

    const int l = tid & 127, grp = tid >> 7;
    float a0 = 0.f, a1 = 0.f, a2 = 0.f, a3 = 0.f;

    for (int c = 0; c < 4; c++) {
        __syncthreads();   // orders hl (c==0) and wl reuse (c>0)
        for (int m = 0; m < 32; m++) {
            const int idx = m * 256 + tid;
            const int lr = idx >> 6, jc = idx & 63;
            wl[lr * 65 + jc] = Wfc[(size_t)lr * H + c * 64 + jc];
        }
        __syncthreads();
#pragma unroll 4
        for (int jc = 0; jc < 64; jc++) {
            const float wv = wl[l * 65 + jc];
            const int hj = c * 64 + jc;
            a0 += hl[(grp * 4 + 0) * 256 + hj] * wv;
            a1 += hl[(grp * 4 + 1) * 256 + hj] * wv;
            a2 += hl[(grp * 4 + 2) * 256 + hj] * wv;
            a3 += hl[(grp * 4 + 3) * 256 + hj] * wv;
        }
    }

    const float bias = bfc[l];
    float accs[4] = {a0, a1, a2, a3};
#pragma unroll
    for (int r = 0; r < 4; r++) {
        const int k = blk * 8 + grp * 4 + r;
        const int t = k >> 6, b = k & 63;
        out[((size_t)b * LL + t) * LBL + l] = accs[r] + bias;
    }
}

// ---------------------------------------------------------------------------
extern "C" void kernel_launch(void* const* d_in, const int* in_sizes, int n_in,
                              void* d_out, int out_size, void* d_ws, size_t ws_size,
                              hipStream_t stream)
{
    const float* x   = (const float*)d_in[0];
    const float* hi  = (const float*)d_in[1];
    const float* Wih = (const float*)d_in[2];
    const float* Whh = (const float*)d_in[3];
    const float* bih = (const float*)d_in[4];
    const float* bhh = (const float*)d_in[5];
    const float* Wfc = (const float*)d_in[6];
    const float* bfc = (const float*)d_in[7];
    float* out = (float*)d_out;

    _Float16* PREh = (_Float16*)d_ws;                        // 8192*1024 fp16 = 16 MB
    ull*      HT   = (ull*)((char*)d_ws +
                            (size_t)NSTEP * GDIM * sizeof(_Float16));  // 8256*256*8 = 16.9 MB

    const size_t need = (size_t)NSTEP * GDIM * sizeof(_Float16)
                      + (size_t)NROW * H * sizeof(ull);
    if (ws_size < need) return;   // visible failure instead of OOB writes

    k_init<<<64, H, 0, stream>>>(HT);
    k_pre<<<dim3(GDIM / 64, LL), 256, 0, stream>>>(x, hi, Wih, bih, bhh, PREh);
    k_rec<<<NWG, 1024, 0, stream>>>(PREh, Wih, Whh, HT);
    k_fc<<<NSTEP / 8, 256, 0, stream>>>(HT, Wfc, bfc, out);
}